// Round 14
// baseline (405.514 us; speedup 1.0000x reference)
//
#include <hip/hip_runtime.h>
#include <hip/hip_bf16.h>

#define NN 50000
#define NE 800000
#define NAF 9
#define NBF 3
#define BN_EPS 1e-5f
#define NBUK 196          // ceil(NN/256) dst buckets
#define CHUNK 8192        // edges staged in LDS per k_bin block
#define NTILE 3125        // NN / 16 row tiles (exact)
#define MMB 1563          // mm grid: 2 row-tiles per block, one-shot
#define AGB 3125          // agg grid: 16 nodes per block (4 per wave)

typedef __attribute__((ext_vector_type(8))) short bf16x8;
typedef __attribute__((ext_vector_type(4))) float f32x4;

__device__ __forceinline__ short f2b(float f) {
  unsigned u = __float_as_uint(f);
  unsigned r = (u + 0x7FFFu + ((u >> 16) & 1u)) >> 16;
  return (short)r;
}

__device__ __forceinline__ float b2f(unsigned short v) {
  return __uint_as_float(((unsigned)v) << 16);
}

__device__ __forceinline__ bf16x8 pack8(float4 a, float4 b) {
  bf16x8 v;
  v[0] = f2b(a.x); v[1] = f2b(a.y); v[2] = f2b(a.z); v[3] = f2b(a.w);
  v[4] = f2b(b.x); v[5] = f2b(b.y); v[6] = f2b(b.z); v[7] = f2b(b.w);
  return v;
}

// ---------------- K0: atom encoder (fp32 h + bf16 copy) ----------------
__global__ __launch_bounds__(256) void k_atom(const int* __restrict__ x,
                                              const float* __restrict__ aemb,
                                              float* __restrict__ h,
                                              unsigned short* __restrict__ hb) {
  int node = (blockIdx.x * 256 + threadIdx.x) >> 6;
  int lane = threadIdx.x & 63;
  if (node >= NN) return;
  const int* xr = x + node * NAF;
  float acc = 0.f;
#pragma unroll
  for (int f = 0; f < NAF; ++f) acc += aemb[(f * 64 + xr[f]) * 64 + lane];
  h[(size_t)node * 64 + lane] = acc;
  hb[(size_t)node * 64 + lane] = (unsigned short)f2b(acc);
}

// -------- weight pre-pack: fragment-layout bf16 for all layers --------
__global__ __launch_bounds__(256) void k_prep(const float* __restrict__ w1,
                                              const float* __restrict__ w2,
                                              bf16x8* __restrict__ pre1,
                                              bf16x8* __restrict__ pre2) {
  int f = (blockIdx.x & 15) * 256 + threadIdx.x;  // 0..4095
  int lane = f & 63, c = lane & 15, g = lane >> 4;
  if (blockIdx.x < 16) {
    int kh = (f >> 6) & 1, t = (f >> 7) & 7, l = f >> 10;
    const float* w = w1 + (size_t)l * 64 * 128;
    bf16x8 v;
#pragma unroll
    for (int j = 0; j < 8; ++j) v[j] = f2b(w[(kh * 32 + g * 8 + j) * 128 + t * 16 + c]);
    pre1[f] = v;
  } else {
    int kf = (f >> 6) & 3, t = (f >> 8) & 3, l = f >> 10;
    const float* w = w2 + (size_t)l * 128 * 64;
    bf16x8 v;
#pragma unroll
    for (int j = 0; j < 8; ++j) v[j] = f2b(w[(kf * 32 + g * 8 + j) * 64 + t * 16 + c]);
    pre2[f] = v;
  }
}

// -------- partial-stats reduce --------
__global__ __launch_bounds__(256) void k_red(const float* __restrict__ partial,
                                             float* __restrict__ st, int width) {
  int col = threadIdx.x;
  if (col >= width) return;
  int per = (MMB + gridDim.x - 1) / gridDim.x;
  int r0 = blockIdx.x * per;
  int r1 = min(MMB, r0 + per);
  float s = 0.f;
  int r = r0;
  for (; r + 4 <= r1; r += 4) {
    s += partial[(size_t)r * width + col] + partial[(size_t)(r + 1) * width + col]
       + partial[(size_t)(r + 2) * width + col] + partial[(size_t)(r + 3) * width + col];
  }
  for (; r < r1; ++r) s += partial[(size_t)r * width + col];
  atomicAdd(&st[col], s);
}

// -------- h prep: in-place BN+ReLU on zB, emit bf16 copy --------
__global__ __launch_bounds__(256) void k_hprep(float* __restrict__ zB,
                                               const float* __restrict__ st,
                                               const float* __restrict__ g,
                                               const float* __restrict__ b,
                                               unsigned short* __restrict__ hb) {
  __shared__ float ns[64], nbv[64];
  if (threadIdx.x < 64) {
    int c = threadIdx.x;
    const float inv = 1.0f / NN;
    float mu = st[c] * inv;
    float var = st[64 + c] * inv - mu * mu;
    float sc = rsqrtf(var + BN_EPS) * g[c];
    ns[c] = sc;
    nbv[c] = b[c] - mu * sc;
  }
  __syncthreads();
  float4* z4 = (float4*)zB;
  ushort4* hb4 = (ushort4*)hb;
  int total = NN * 16;
  for (int i = blockIdx.x * 256 + threadIdx.x; i < total; i += gridDim.x * 256) {
    float4 v = z4[i];
    int c = (i & 15) * 4;
    v.x = fmaxf(fmaf(v.x, ns[c], nbv[c]), 0.f);
    v.y = fmaxf(fmaf(v.y, ns[c + 1], nbv[c + 1]), 0.f);
    v.z = fmaxf(fmaf(v.z, ns[c + 2], nbv[c + 2]), 0.f);
    v.w = fmaxf(fmaf(v.w, ns[c + 3], nbv[c + 3]), 0.f);
    z4[i] = v;
    ushort4 o;
    o.x = (unsigned short)f2b(v.x);
    o.y = (unsigned short)f2b(v.y);
    o.z = (unsigned short)f2b(v.z);
    o.w = (unsigned short)f2b(v.w);
    hb4[i] = o;
  }
}

// ---------------- CSR build: bucket hist -> scan -> bin -> finAll ----------------
__global__ __launch_bounds__(256) void k_hist2(const int* __restrict__ ei,
                                               int* __restrict__ bcnt) {
  __shared__ int lh[NBUK];
  for (int i = threadIdx.x; i < NBUK; i += 256) lh[i] = 0;
  __syncthreads();
  for (int e = blockIdx.x * 256 + threadIdx.x; e < NE; e += gridDim.x * 256)
    atomicAdd(&lh[ei[NE + e] >> 8], 1);
  __syncthreads();
  for (int i = threadIdx.x; i < NBUK; i += 256)
    if (lh[i]) atomicAdd(&bcnt[i], lh[i]);
}

__global__ __launch_bounds__(256) void k_scanb(const int* __restrict__ bcnt,
                                               int* __restrict__ bbase,
                                               int* __restrict__ bfill) {
  int tid = threadIdx.x;
  int c = (tid < NBUK) ? bcnt[tid] : 0;
  int lane = tid & 63, wid = tid >> 6;
  int inc = c;
#pragma unroll
  for (int off = 1; off < 64; off <<= 1) {
    int t = __shfl_up(inc, off);
    if (lane >= off) inc += t;
  }
  __shared__ int wt[4];
  if (lane == 63) wt[wid] = inc;
  __syncthreads();
  int woff = 0;
#pragma unroll
  for (int w = 0; w < 4; ++w) woff += (w < wid) ? wt[w] : 0;
  if (tid < NBUK) { int e = inc - c + woff; bbase[tid] = e; bfill[tid] = e; }
}

// bin: read ei/ea directly, build payload, LDS-stage, dense bucket writes
__global__ __launch_bounds__(1024) void k_bin2(const int* __restrict__ ei,
                                               const int* __restrict__ ea,
                                               int* __restrict__ bfill,
                                               uint2* __restrict__ binned) {
  __shared__ uint2 st[CHUNK];     // 64 KB
  __shared__ int lh[NBUK];
  __shared__ int gbase[NBUK];
  int tid = threadIdx.x;
  int base = blockIdx.x * CHUNK;
  int n = NE - base; if (n > CHUNK) n = CHUNK;
  for (int i = tid; i < NBUK; i += 1024) lh[i] = 0;
  __syncthreads();
  for (int i = tid; i < n; i += 1024) {
    int e = base + i;
    int src = ei[e];
    int dst = ei[NE + e];
    unsigned code = (unsigned)(ea[e * 3] | (ea[e * 3 + 1] << 3) | (ea[e * 3 + 2] << 6));
    st[i] = make_uint2((unsigned)src | (code << 17), (unsigned)dst);
    atomicAdd(&lh[dst >> 8], 1);
  }
  __syncthreads();
  for (int i = tid; i < NBUK; i += 1024) {
    int c = lh[i];
    gbase[i] = c ? atomicAdd(&bfill[i], c) : 0;
  }
  __syncthreads();
  for (int i = tid; i < NBUK; i += 1024) lh[i] = 0;
  __syncthreads();
  for (int i = tid; i < n; i += 1024) {
    uint2 p = st[i];
    int b = p.y >> 8;
    int r = atomicAdd(&lh[b], 1);
    binned[gbase[b] + r] = p;
  }
}

// finAll: per bucket: LDS count -> local scan -> row_ptr -> scatter.
__global__ __launch_bounds__(1024) void k_finAll(const uint2* __restrict__ binned,
                                                 const int* __restrict__ bbase,
                                                 const int* __restrict__ bcnt,
                                                 int* __restrict__ row_ptr,
                                                 unsigned* __restrict__ epack) {
  __shared__ int cnt[256];
  __shared__ int cur[256];
  __shared__ int wt[4];
  int b = blockIdx.x, tid = threadIdx.x;
  if (tid < 256) cnt[tid] = 0;
  __syncthreads();
  int s = bbase[b], n = bcnt[b];
  for (int i = tid; i < n; i += 1024) atomicAdd(&cnt[binned[s + i].y & 255], 1);
  __syncthreads();
  int lane = tid & 63, w = tid >> 6;
  int c = 0, inc = 0;
  if (tid < 256) {
    c = cnt[tid];
    inc = c;
#pragma unroll
    for (int off = 1; off < 64; off <<= 1) {
      int t = __shfl_up(inc, off);
      if (lane >= off) inc += t;
    }
    if (lane == 63) wt[w] = inc;
  }
  __syncthreads();
  if (tid < 256) {
    int woff = 0;
#pragma unroll
    for (int i = 0; i < 4; ++i) woff += (i < w) ? wt[i] : 0;
    int excl = s + inc - c + woff;
    int node = (b << 8) + tid;
    if (node < NN) row_ptr[node] = excl;
    cur[tid] = excl;
  }
  if (b == NBUK - 1 && tid == 0) row_ptr[NN] = NE;
  __syncthreads();
  for (int i = tid; i < n; i += 1024) {
    uint2 p = binned[s + i];
    int pos = atomicAdd(&cur[p.y & 255], 1);
    epack[pos] = p.x;
  }
}

// ------------- aggregation: bf16 gather, pre-summed tables, pair-interleaved -----
// 16 nodes per block, 4 per wave processed as 2 interleaved pairs -> 8 gathers
// in flight per 16-lane group during the merged main loop.
__global__ __launch_bounds__(256) void k_agg(const float* __restrict__ hf,
                                             const unsigned short* __restrict__ hb,
                                             const float* __restrict__ bemb,
                                             const float* __restrict__ eps, int l,
                                             const int* __restrict__ row_ptr,
                                             const unsigned* __restrict__ epack,
                                             float* __restrict__ z) {
  __shared__ float t12[64 * 68];  // feat0+feat1 pre-sum, padded stride 68
  __shared__ float t3[8 * 68];
  const float* bt = bemb + (size_t)l * NBF * 8 * 64;
  const float4* bt4 = (const float4*)bt;
  for (int i = threadIdx.x; i < 64 * 16; i += 256) {
    int combo = i >> 4, ch4 = i & 15;
    float4 a = bt4[(combo & 7) * 16 + ch4];
    float4 b = bt4[128 + (combo >> 3) * 16 + ch4];
    float4 sum;
    sum.x = a.x + b.x; sum.y = a.y + b.y; sum.z = a.z + b.z; sum.w = a.w + b.w;
    *(float4*)(t12 + combo * 68 + ch4 * 4) = sum;
  }
  for (int i = threadIdx.x; i < 8 * 16; i += 256) {
    int row = i >> 4, ch4 = i & 15;
    *(float4*)(t3 + row * 68 + ch4 * 4) = bt4[256 + row * 16 + ch4];
  }
  __syncthreads();
  const char* hbb = (const char*)hb;
  const float4* hf4 = (const float4*)hf;

  int lane = threadIdx.x & 63;
  int wid = threadIdx.x >> 6;
  int gr = lane >> 4;
  int c4 = lane & 15;
  int nbase = blockIdx.x * 16 + wid * 4;
  float se = 1.0f + eps[l];

#pragma unroll
  for (int j = 0; j < 2; ++j) {
    int n0 = nbase + j * 2;
    int n1 = n0 + 1;
    int rp0 = row_ptr[n0], rp1 = row_ptr[n1], rp2 = row_ptr[n1 + 1];
    int i0 = rp0 + gr, e0 = rp1;
    int i1 = rp1 + gr, e1 = rp2;
    float4 acc0 = {0.f, 0.f, 0.f, 0.f};
    float4 acc1 = {0.f, 0.f, 0.f, 0.f};

    auto edge = [&](float4& acc, unsigned p, ushort4 hv) {
      unsigned cd = p >> 17;
      float4 e12 = *(const float4*)(t12 + (cd & 63) * 68 + c4 * 4);
      float4 e3 = *(const float4*)(t3 + (cd >> 6) * 68 + c4 * 4);
      acc.x += fmaxf(b2f(hv.x) + e12.x + e3.x, 0.f);
      acc.y += fmaxf(b2f(hv.y) + e12.y + e3.y, 0.f);
      acc.z += fmaxf(b2f(hv.z) + e12.z + e3.z, 0.f);
      acc.w += fmaxf(b2f(hv.w) + e12.w + e3.w, 0.f);
    };
    auto ld = [&](unsigned p) {
      return *(const ushort4*)(hbb + ((p & 0x1FFFFu) * 128u + c4 * 8u));
    };

    // interleaved main: 8 h-gathers in flight
    while (i0 + 12 < e0 && i1 + 12 < e1) {
      unsigned p00 = epack[i0], p01 = epack[i0 + 4], p02 = epack[i0 + 8], p03 = epack[i0 + 12];
      unsigned p10 = epack[i1], p11 = epack[i1 + 4], p12 = epack[i1 + 8], p13 = epack[i1 + 12];
      ushort4 h00 = ld(p00), h01 = ld(p01), h02 = ld(p02), h03 = ld(p03);
      ushort4 h10 = ld(p10), h11 = ld(p11), h12 = ld(p12), h13 = ld(p13);
      edge(acc0, p00, h00); edge(acc0, p01, h01); edge(acc0, p02, h02); edge(acc0, p03, h03);
      edge(acc1, p10, h10); edge(acc1, p11, h11); edge(acc1, p12, h12); edge(acc1, p13, h13);
      i0 += 16; i1 += 16;
    }
    // drain node0
    for (; i0 + 12 < e0; i0 += 16) {
      unsigned p0 = epack[i0], p1 = epack[i0 + 4], p2 = epack[i0 + 8], p3 = epack[i0 + 12];
      ushort4 h0 = ld(p0), h1 = ld(p1), h2 = ld(p2), h3 = ld(p3);
      edge(acc0, p0, h0); edge(acc0, p1, h1); edge(acc0, p2, h2); edge(acc0, p3, h3);
    }
    for (; i0 < e0; i0 += 4) {
      unsigned p0 = epack[i0];
      edge(acc0, p0, ld(p0));
    }
    // drain node1
    for (; i1 + 12 < e1; i1 += 16) {
      unsigned p0 = epack[i1], p1 = epack[i1 + 4], p2 = epack[i1 + 8], p3 = epack[i1 + 12];
      ushort4 h0 = ld(p0), h1 = ld(p1), h2 = ld(p2), h3 = ld(p3);
      edge(acc1, p0, h0); edge(acc1, p1, h1); edge(acc1, p2, h2); edge(acc1, p3, h3);
    }
    for (; i1 < e1; i1 += 4) {
      unsigned p0 = epack[i1];
      edge(acc1, p0, ld(p0));
    }
#pragma unroll
    for (int off = 16; off <= 32; off <<= 1) {
      acc0.x += __shfl_xor(acc0.x, off);
      acc0.y += __shfl_xor(acc0.y, off);
      acc0.z += __shfl_xor(acc0.z, off);
      acc0.w += __shfl_xor(acc0.w, off);
      acc1.x += __shfl_xor(acc1.x, off);
      acc1.y += __shfl_xor(acc1.y, off);
      acc1.z += __shfl_xor(acc1.z, off);
      acc1.w += __shfl_xor(acc1.w, off);
    }
    if (gr == 0) {
      float4 s0 = hf4[(size_t)n0 * 16 + c4];
      float4 s1 = hf4[(size_t)n1 * 16 + c4];
      float4 o0, o1;
      o0.x = fmaf(s0.x, se, acc0.x); o0.y = fmaf(s0.y, se, acc0.y);
      o0.z = fmaf(s0.z, se, acc0.z); o0.w = fmaf(s0.w, se, acc0.w);
      o1.x = fmaf(s1.x, se, acc1.x); o1.y = fmaf(s1.y, se, acc1.y);
      o1.z = fmaf(s1.z, se, acc1.z); o1.w = fmaf(s1.w, se, acc1.w);
      ((float4*)z)[(size_t)n0 * 16 + c4] = o0;
      ((float4*)z)[(size_t)n1 * 16 + c4] = o1;
    }
  }
}

// ------------- MFMA gemm1: z[NN,64] @ w1 + b1 -> y(fp32) ; BN1 partials -----
__global__ __launch_bounds__(256) void k_mm1(const float* __restrict__ z,
                                             const bf16x8* __restrict__ pre1,
                                             const float* __restrict__ b1,
                                             int l, float* __restrict__ y,
                                             float* __restrict__ part1) {
  __shared__ float lz[2][16 * 68];  // 8.7 KB
  int tid = threadIdx.x;
  int lane = tid & 63;
  int wid = tid >> 6;
  int c = lane & 15;
  int g = lane >> 4;

  int t0 = blockIdx.x * 2;
  int ntl = (t0 + 1 < NTILE) ? 2 : 1;

  const float4* zt = (const float4*)(z + (size_t)t0 * 16 * 64);
  int nf4 = ntl * 256;
  for (int i = tid; i < nf4; i += 256) {
    float4 v = zt[i];
    int tile = i >> 8;
    int f4 = i & 255;
    int row = f4 >> 4, c4i = f4 & 15;
    *(float4*)(&lz[tile][row * 68 + c4i * 4]) = v;
  }

  bf16x8 Bf[2][2];
#pragma unroll
  for (int u = 0; u < 2; ++u)
#pragma unroll
    for (int kh = 0; kh < 2; ++kh)
      Bf[u][kh] = pre1[(((size_t)l * 8 + wid * 2 + u) * 2 + kh) * 64 + lane];
  float bias0 = b1[l * 128 + (wid * 2) * 16 + c];
  float bias1 = b1[l * 128 + (wid * 2 + 1) * 16 + c];

  __syncthreads();

  float ssum0 = 0.f, ssum1 = 0.f, sq0 = 0.f, sq1 = 0.f;

#pragma unroll
  for (int u = 0; u < 2; ++u) {
    if (u >= ntl) break;
    int rowbase = (t0 + u) * 16;
    const float* myz = lz[u];
    float4 q0 = *(const float4*)(myz + c * 68 + g * 8);
    float4 q1 = *(const float4*)(myz + c * 68 + g * 8 + 4);
    float4 q2 = *(const float4*)(myz + c * 68 + 32 + g * 8);
    float4 q3 = *(const float4*)(myz + c * 68 + 32 + g * 8 + 4);
    bf16x8 a0 = pack8(q0, q1);
    bf16x8 a1 = pack8(q2, q3);

    f32x4 acc0 = {bias0, bias0, bias0, bias0};
    acc0 = __builtin_amdgcn_mfma_f32_16x16x32_bf16(a0, Bf[0][0], acc0, 0, 0, 0);
    acc0 = __builtin_amdgcn_mfma_f32_16x16x32_bf16(a1, Bf[0][1], acc0, 0, 0, 0);
    f32x4 acc1 = {bias1, bias1, bias1, bias1};
    acc1 = __builtin_amdgcn_mfma_f32_16x16x32_bf16(a0, Bf[1][0], acc1, 0, 0, 0);
    acc1 = __builtin_amdgcn_mfma_f32_16x16x32_bf16(a1, Bf[1][1], acc1, 0, 0, 0);

    int tc0 = wid * 2, tc1 = wid * 2 + 1;
#pragma unroll
    for (int r = 0; r < 4; ++r) {
      float v0 = acc0[r], v1 = acc1[r];
      y[(size_t)(rowbase + g * 4 + r) * 128 + tc0 * 16 + c] = v0;
      y[(size_t)(rowbase + g * 4 + r) * 128 + tc1 * 16 + c] = v1;
      ssum0 += v0; sq0 = fmaf(v0, v0, sq0);
      ssum1 += v1; sq1 = fmaf(v1, v1, sq1);
    }
  }
  ssum0 += __shfl_xor(ssum0, 16); ssum0 += __shfl_xor(ssum0, 32);
  ssum1 += __shfl_xor(ssum1, 16); ssum1 += __shfl_xor(ssum1, 32);
  sq0 += __shfl_xor(sq0, 16); sq0 += __shfl_xor(sq0, 32);
  sq1 += __shfl_xor(sq1, 16); sq1 += __shfl_xor(sq1, 32);
  if (g == 0) {
    float* pp = part1 + (size_t)blockIdx.x * 256;
    pp[(wid * 2) * 16 + c] = ssum0;
    pp[(wid * 2 + 1) * 16 + c] = ssum1;
    pp[128 + (wid * 2) * 16 + c] = sq0;
    pp[128 + (wid * 2 + 1) * 16 + c] = sq1;
  }
}

// ---- MFMA gemm2: relu(bn1(y))[NN,128] @ w2 + b2 -> z2 ; BN2 partials --
__global__ __launch_bounds__(256) void k_mm2(const float* __restrict__ y,
                                             const bf16x8* __restrict__ pre2,
                                             const float* __restrict__ b2,
                                             const float* __restrict__ g1,
                                             const float* __restrict__ bb1,
                                             int l, float* __restrict__ z2,
                                             const float* __restrict__ st1,
                                             float* __restrict__ part2) {
  __shared__ float ly[2][16 * 132];  // 16.9 KB
  __shared__ float ns[128], nb[128];
  int tid = threadIdx.x;
  int lane = tid & 63;
  int wid = tid >> 6;
  int c = lane & 15;
  int g = lane >> 4;

  int t0 = blockIdx.x * 2;
  int ntl = (t0 + 1 < NTILE) ? 2 : 1;

  const float4* yt = (const float4*)(y + (size_t)t0 * 16 * 128);
  int nf4 = ntl * 512;
  for (int i = tid; i < nf4; i += 256) {
    float4 v = yt[i];
    int tile = i >> 9;
    int f4 = i & 511;
    int row = f4 >> 5, c4i = f4 & 31;
    *(float4*)(&ly[tile][row * 132 + c4i * 4]) = v;
  }

  if (tid < 128) {
    int ch = tid;
    const float inv = 1.0f / NN;
    float mu = st1[ch] * inv;
    float var = st1[128 + ch] * inv - mu * mu;
    float sc = rsqrtf(var + BN_EPS) * g1[l * 128 + ch];
    ns[ch] = sc;
    nb[ch] = bb1[l * 128 + ch] - mu * sc;
  }

  bf16x8 Bf[4];
#pragma unroll
  for (int kf = 0; kf < 4; ++kf)
    Bf[kf] = pre2[(((size_t)l * 4 + wid) * 4 + kf) * 64 + lane];
  float bias = b2[l * 64 + wid * 16 + c];

  __syncthreads();

  const float4* nsf = (const float4*)ns;
  const float4* nbf = (const float4*)nb;
  float ssum = 0.f, sq = 0.f;

#pragma unroll
  for (int u = 0; u < 2; ++u) {
    if (u >= ntl) break;
    int rowbase = (t0 + u) * 16;
    const float* myy = ly[u];
    bf16x8 A[4];
#pragma unroll
    for (int kf = 0; kf < 4; ++kf) {
      float4 q0 = *(const float4*)(myy + c * 132 + kf * 32 + g * 8);
      float4 q1 = *(const float4*)(myy + c * 132 + kf * 32 + g * 8 + 4);
      float4 s0 = nsf[kf * 8 + g * 2];
      float4 s1 = nsf[kf * 8 + g * 2 + 1];
      float4 o0 = nbf[kf * 8 + g * 2];
      float4 o1 = nbf[kf * 8 + g * 2 + 1];
      float4 v0, v1;
      v0.x = fmaxf(fmaf(q0.x, s0.x, o0.x), 0.f);
      v0.y = fmaxf(fmaf(q0.y, s0.y, o0.y), 0.f);
      v0.z = fmaxf(fmaf(q0.z, s0.z, o0.z), 0.f);
      v0.w = fmaxf(fmaf(q0.w, s0.w, o0.w), 0.f);
      v1.x = fmaxf(fmaf(q1.x, s1.x, o1.x), 0.f);
      v1.y = fmaxf(fmaf(q1.y, s1.y, o1.y), 0.f);
      v1.z = fmaxf(fmaf(q1.z, s1.z, o1.z), 0.f);
      v1.w = fmaxf(fmaf(q1.w, s1.w, o1.w), 0.f);
      A[kf] = pack8(v0, v1);
    }
    f32x4 acc = {bias, bias, bias, bias};
#pragma unroll
    for (int kf = 0; kf < 4; ++kf)
      acc = __builtin_amdgcn_mfma_f32_16x16x32_bf16(A[kf], Bf[kf], acc, 0, 0, 0);
#pragma unroll
    for (int r = 0; r < 4; ++r) {
      float v = acc[r];
      z2[(size_t)(rowbase + g * 4 + r) * 64 + wid * 16 + c] = v;
      ssum += v; sq = fmaf(v, v, sq);
    }
  }
  ssum += __shfl_xor(ssum, 16); ssum += __shfl_xor(ssum, 32);
  sq += __shfl_xor(sq, 16); sq += __shfl_xor(sq, 32);
  if (g == 0) {
    float* pp = part2 + (size_t)blockIdx.x * 128;
    pp[wid * 16 + c] = ssum;
    pp[64 + wid * 16 + c] = sq;
  }
}

// ------------- final BN2 apply (no relu) -> d_out -------------
__global__ __launch_bounds__(256) void k_bn2(const float* __restrict__ z2,
                                             const float* __restrict__ g,
                                             const float* __restrict__ b,
                                             const float* __restrict__ st,
                                             float* __restrict__ h) {
  __shared__ float ns[64], nb[64];
  if (threadIdx.x < 64) {
    int c = threadIdx.x;
    const float inv = 1.0f / NN;
    float mu = st[c] * inv;
    float var = st[64 + c] * inv - mu * mu;
    float sc = rsqrtf(var + BN_EPS) * g[c];
    ns[c] = sc;
    nb[c] = b[c] - mu * sc;
  }
  __syncthreads();
  const float4* zin = (const float4*)z2;
  float4* hout = (float4*)h;
  int total = NN * 16;
  for (int i = blockIdx.x * 256 + threadIdx.x; i < total; i += gridDim.x * 256) {
    float4 v = zin[i];
    int c = (i & 15) * 4;
    v.x = fmaf(v.x, ns[c], nb[c]);
    v.y = fmaf(v.y, ns[c + 1], nb[c + 1]);
    v.z = fmaf(v.z, ns[c + 2], nb[c + 2]);
    v.w = fmaf(v.w, ns[c + 3], nb[c + 3]);
    hout[i] = v;
  }
}

extern "C" void kernel_launch(void* const* d_in, const int* in_sizes, int n_in,
                              void* d_out, int out_size, void* d_ws, size_t ws_size,
                              hipStream_t stream) {
  const int* x = (const int*)d_in[0];
  const int* ei = (const int*)d_in[1];
  const int* ea = (const int*)d_in[2];
  const float* aemb = (const float*)d_in[3];
  const float* bemb = (const float*)d_in[4];
  const float* l1w = (const float*)d_in[5];
  const float* l1b = (const float*)d_in[6];
  const float* g1 = (const float*)d_in[7];
  const float* bb1 = (const float*)d_in[8];
  const float* l2w = (const float*)d_in[9];
  const float* l2b = (const float*)d_in[10];
  const float* eps = (const float*)d_in[11];
  const float* bng = (const float*)d_in[12];
  const float* bnb = (const float*)d_in[13];
  float* out = (float*)d_out;

  char* p = (char*)d_ws;
  float* zA = (float*)p;           p += (size_t)NN * 64 * 4;    // agg out
  float* y = (float*)p;            p += (size_t)NN * 128 * 4;   // y(fp32); hb+binned alias
  float* zB = (float*)p;           p += (size_t)NN * 64 * 4;    // gemm2 out / h (in-place BN)
  unsigned* epack = (unsigned*)p;  p += (size_t)NE * 4;
  int* row_ptr = (int*)p;          p += (size_t)(NN + 1) * 4;
  int* bcnt = (int*)p;             p += 256 * 4;
  int* bbase = (int*)p;            p += 256 * 4;
  int* bfill = (int*)p;            p += 256 * 4;
  float* stats = (float*)p;        p += 4 * 384 * 4;
  bf16x8* pre1 = (bf16x8*)p;       p += 4096 * 16;
  bf16x8* pre2 = (bf16x8*)p;       p += 4096 * 16;
  float* part1 = (float*)p;        p += (size_t)MMB * 256 * 4;
  float* part2 = (float*)p;        p += (size_t)MMB * 128 * 4;

  uint2* binned = (uint2*)y;                // CSR phase only
  unsigned short* hb = (unsigned short*)y;  // bf16 h copy (pre-mm1 phase)
  float* h0 = zB;

  hipMemsetAsync(bcnt, 0, 3 * 256 * 4 + 4 * 384 * 4, stream);

  k_prep<<<32, 256, 0, stream>>>(l1w, l2w, pre1, pre2);
  k_hist2<<<256, 256, 0, stream>>>(ei, bcnt);
  k_scanb<<<1, 256, 0, stream>>>(bcnt, bbase, bfill);
  k_bin2<<<(NE + CHUNK - 1) / CHUNK, 1024, 0, stream>>>(ei, ea, bfill, binned);
  k_finAll<<<NBUK, 1024, 0, stream>>>(binned, bbase, bcnt, row_ptr, epack);

  k_atom<<<NN / 4, 256, 0, stream>>>(x, aemb, h0, hb);

  for (int l = 0; l < 4; ++l) {
    float* st1 = stats + l * 384;
    float* st2 = st1 + 256;
    if (l > 0) {
      const float* stp = stats + (l - 1) * 384 + 256;
      k_hprep<<<1024, 256, 0, stream>>>(zB, stp, bng + (l - 1) * 64,
                                        bnb + (l - 1) * 64, hb);
    }
    k_agg<<<AGB, 256, 0, stream>>>(zB, hb, bemb, eps, l, row_ptr, epack, zA);
    k_mm1<<<MMB, 256, 0, stream>>>(zA, pre1, l1b, l, y, part1);
    k_red<<<32, 256, 0, stream>>>(part1, st1, 256);
    k_mm2<<<MMB, 256, 0, stream>>>(y, pre2, l2b, g1, bb1, l, zB, st1, part2);
    k_red<<<32, 256, 0, stream>>>(part2, st2, 128);
  }
  k_bn2<<<1024, 256, 0, stream>>>(zB, bng + 3 * 64, bnb + 3 * 64,
                                  stats + 3 * 384 + 256, out);
}

// Round 15
// 377.092 us; speedup vs baseline: 1.0754x; 1.0754x over previous
//
#include <hip/hip_runtime.h>
#include <hip/hip_bf16.h>

#define NN 50000
#define NE 800000
#define NAF 9
#define NBF 3
#define BN_EPS 1e-5f
#define NBUK 196          // ceil(NN/256) dst buckets
#define CHUNK 8192        // edges staged in LDS per k_bin block
#define NTILE 3125        // NN / 16 row tiles (exact)
#define MMB 1563          // mm grid: 2 row-tiles per block, one-shot
#define AGB 3125          // agg grid: 16 nodes per block (4 per wave)

typedef __attribute__((ext_vector_type(8))) short bf16x8;
typedef __attribute__((ext_vector_type(4))) float f32x4;

__device__ __forceinline__ short f2b(float f) {
  unsigned u = __float_as_uint(f);
  unsigned r = (u + 0x7FFFu + ((u >> 16) & 1u)) >> 16;
  return (short)r;
}

__device__ __forceinline__ float b2f(unsigned short v) {
  return __uint_as_float(((unsigned)v) << 16);
}

__device__ __forceinline__ bf16x8 pack8(float4 a, float4 b) {
  bf16x8 v;
  v[0] = f2b(a.x); v[1] = f2b(a.y); v[2] = f2b(a.z); v[3] = f2b(a.w);
  v[4] = f2b(b.x); v[5] = f2b(b.y); v[6] = f2b(b.z); v[7] = f2b(b.w);
  return v;
}

// ---------------- K0: atom encoder (fp32 h + bf16 copy) ----------------
__global__ __launch_bounds__(256) void k_atom(const int* __restrict__ x,
                                              const float* __restrict__ aemb,
                                              float* __restrict__ h,
                                              unsigned short* __restrict__ hb) {
  int node = (blockIdx.x * 256 + threadIdx.x) >> 6;
  int lane = threadIdx.x & 63;
  if (node >= NN) return;
  const int* xr = x + node * NAF;
  float acc = 0.f;
#pragma unroll
  for (int f = 0; f < NAF; ++f) acc += aemb[(f * 64 + xr[f]) * 64 + lane];
  h[(size_t)node * 64 + lane] = acc;
  hb[(size_t)node * 64 + lane] = (unsigned short)f2b(acc);
}

// -------- weight pre-pack: fragment-layout bf16 for all layers --------
__global__ __launch_bounds__(256) void k_prep(const float* __restrict__ w1,
                                              const float* __restrict__ w2,
                                              bf16x8* __restrict__ pre1,
                                              bf16x8* __restrict__ pre2) {
  int f = (blockIdx.x & 15) * 256 + threadIdx.x;  // 0..4095
  int lane = f & 63, c = lane & 15, g = lane >> 4;
  if (blockIdx.x < 16) {
    int kh = (f >> 6) & 1, t = (f >> 7) & 7, l = f >> 10;
    const float* w = w1 + (size_t)l * 64 * 128;
    bf16x8 v;
#pragma unroll
    for (int j = 0; j < 8; ++j) v[j] = f2b(w[(kh * 32 + g * 8 + j) * 128 + t * 16 + c]);
    pre1[f] = v;
  } else {
    int kf = (f >> 6) & 3, t = (f >> 8) & 3, l = f >> 10;
    const float* w = w2 + (size_t)l * 128 * 64;
    bf16x8 v;
#pragma unroll
    for (int j = 0; j < 8; ++j) v[j] = f2b(w[(kf * 32 + g * 8 + j) * 64 + t * 16 + c]);
    pre2[f] = v;
  }
}

// -------- partial-stats reduce --------
__global__ __launch_bounds__(256) void k_red(const float* __restrict__ partial,
                                             float* __restrict__ st, int width) {
  int col = threadIdx.x;
  if (col >= width) return;
  int per = (MMB + gridDim.x - 1) / gridDim.x;
  int r0 = blockIdx.x * per;
  int r1 = min(MMB, r0 + per);
  float s = 0.f;
  int r = r0;
  for (; r + 4 <= r1; r += 4) {
    s += partial[(size_t)r * width + col] + partial[(size_t)(r + 1) * width + col]
       + partial[(size_t)(r + 2) * width + col] + partial[(size_t)(r + 3) * width + col];
  }
  for (; r < r1; ++r) s += partial[(size_t)r * width + col];
  atomicAdd(&st[col], s);
}

// -------- h prep: read raw zB, emit bf16 BN+ReLU copy (zB left raw) --------
__global__ __launch_bounds__(256) void k_hprep(const float* __restrict__ zB,
                                               const float* __restrict__ st,
                                               const float* __restrict__ g,
                                               const float* __restrict__ b,
                                               unsigned short* __restrict__ hb) {
  __shared__ float ns[64], nbv[64];
  if (threadIdx.x < 64) {
    int c = threadIdx.x;
    const float inv = 1.0f / NN;
    float mu = st[c] * inv;
    float var = st[64 + c] * inv - mu * mu;
    float sc = rsqrtf(var + BN_EPS) * g[c];
    ns[c] = sc;
    nbv[c] = b[c] - mu * sc;
  }
  __syncthreads();
  const float4* z4 = (const float4*)zB;
  ushort4* hb4 = (ushort4*)hb;
  int total = NN * 16;
  for (int i = blockIdx.x * 256 + threadIdx.x; i < total; i += gridDim.x * 256) {
    float4 v = z4[i];
    int c = (i & 15) * 4;
    v.x = fmaxf(fmaf(v.x, ns[c], nbv[c]), 0.f);
    v.y = fmaxf(fmaf(v.y, ns[c + 1], nbv[c + 1]), 0.f);
    v.z = fmaxf(fmaf(v.z, ns[c + 2], nbv[c + 2]), 0.f);
    v.w = fmaxf(fmaf(v.w, ns[c + 3], nbv[c + 3]), 0.f);
    ushort4 o;
    o.x = (unsigned short)f2b(v.x);
    o.y = (unsigned short)f2b(v.y);
    o.z = (unsigned short)f2b(v.z);
    o.w = (unsigned short)f2b(v.w);
    hb4[i] = o;
  }
}

// ---------------- CSR build: bucket hist -> scan -> bin -> finAll ----------------
__global__ __launch_bounds__(256) void k_hist2(const int* __restrict__ ei,
                                               int* __restrict__ bcnt) {
  __shared__ int lh[NBUK];
  for (int i = threadIdx.x; i < NBUK; i += 256) lh[i] = 0;
  __syncthreads();
  for (int e = blockIdx.x * 256 + threadIdx.x; e < NE; e += gridDim.x * 256)
    atomicAdd(&lh[ei[NE + e] >> 8], 1);
  __syncthreads();
  for (int i = threadIdx.x; i < NBUK; i += 256)
    if (lh[i]) atomicAdd(&bcnt[i], lh[i]);
}

__global__ __launch_bounds__(256) void k_scanb(const int* __restrict__ bcnt,
                                               int* __restrict__ bbase,
                                               int* __restrict__ bfill) {
  int tid = threadIdx.x;
  int c = (tid < NBUK) ? bcnt[tid] : 0;
  int lane = tid & 63, wid = tid >> 6;
  int inc = c;
#pragma unroll
  for (int off = 1; off < 64; off <<= 1) {
    int t = __shfl_up(inc, off);
    if (lane >= off) inc += t;
  }
  __shared__ int wt[4];
  if (lane == 63) wt[wid] = inc;
  __syncthreads();
  int woff = 0;
#pragma unroll
  for (int w = 0; w < 4; ++w) woff += (w < wid) ? wt[w] : 0;
  if (tid < NBUK) { int e = inc - c + woff; bbase[tid] = e; bfill[tid] = e; }
}

// bin: read ei/ea directly, build payload, LDS-stage, dense bucket writes
__global__ __launch_bounds__(1024) void k_bin2(const int* __restrict__ ei,
                                               const int* __restrict__ ea,
                                               int* __restrict__ bfill,
                                               uint2* __restrict__ binned) {
  __shared__ uint2 st[CHUNK];     // 64 KB
  __shared__ int lh[NBUK];
  __shared__ int gbase[NBUK];
  int tid = threadIdx.x;
  int base = blockIdx.x * CHUNK;
  int n = NE - base; if (n > CHUNK) n = CHUNK;
  for (int i = tid; i < NBUK; i += 1024) lh[i] = 0;
  __syncthreads();
  for (int i = tid; i < n; i += 1024) {
    int e = base + i;
    int src = ei[e];
    int dst = ei[NE + e];
    unsigned code = (unsigned)(ea[e * 3] | (ea[e * 3 + 1] << 3) | (ea[e * 3 + 2] << 6));
    st[i] = make_uint2((unsigned)src | (code << 17), (unsigned)dst);
    atomicAdd(&lh[dst >> 8], 1);
  }
  __syncthreads();
  for (int i = tid; i < NBUK; i += 1024) {
    int c = lh[i];
    gbase[i] = c ? atomicAdd(&bfill[i], c) : 0;
  }
  __syncthreads();
  for (int i = tid; i < NBUK; i += 1024) lh[i] = 0;
  __syncthreads();
  for (int i = tid; i < n; i += 1024) {
    uint2 p = st[i];
    int b = p.y >> 8;
    int r = atomicAdd(&lh[b], 1);
    binned[gbase[b] + r] = p;
  }
}

// finAll: per bucket: LDS count -> local scan -> row_ptr -> scatter.
__global__ __launch_bounds__(1024) void k_finAll(const uint2* __restrict__ binned,
                                                 const int* __restrict__ bbase,
                                                 const int* __restrict__ bcnt,
                                                 int* __restrict__ row_ptr,
                                                 unsigned* __restrict__ epack) {
  __shared__ int cnt[256];
  __shared__ int cur[256];
  __shared__ int wt[4];
  int b = blockIdx.x, tid = threadIdx.x;
  if (tid < 256) cnt[tid] = 0;
  __syncthreads();
  int s = bbase[b], n = bcnt[b];
  for (int i = tid; i < n; i += 1024) atomicAdd(&cnt[binned[s + i].y & 255], 1);
  __syncthreads();
  int lane = tid & 63, w = tid >> 6;
  int c = 0, inc = 0;
  if (tid < 256) {
    c = cnt[tid];
    inc = c;
#pragma unroll
    for (int off = 1; off < 64; off <<= 1) {
      int t = __shfl_up(inc, off);
      if (lane >= off) inc += t;
    }
    if (lane == 63) wt[w] = inc;
  }
  __syncthreads();
  if (tid < 256) {
    int woff = 0;
#pragma unroll
    for (int i = 0; i < 4; ++i) woff += (i < w) ? wt[i] : 0;
    int excl = s + inc - c + woff;
    int node = (b << 8) + tid;
    if (node < NN) row_ptr[node] = excl;
    cur[tid] = excl;
  }
  if (b == NBUK - 1 && tid == 0) row_ptr[NN] = NE;
  __syncthreads();
  for (int i = tid; i < n; i += 1024) {
    uint2 p = binned[s + i];
    int pos = atomicAdd(&cur[p.y & 255], 1);
    epack[pos] = p.x;
  }
}

// ------------- aggregation: bf16 gather + pre-summed bond tables -------------
// 16 nodes per block (4 per wave, sequential). Self-term BN+ReLU applied
// inline (hasbn) so hprep need not rewrite zB.
__global__ __launch_bounds__(256) void k_agg(const float* __restrict__ hf,
                                             const unsigned short* __restrict__ hb,
                                             const float* __restrict__ bemb,
                                             const float* __restrict__ eps, int l,
                                             const int* __restrict__ row_ptr,
                                             const unsigned* __restrict__ epack,
                                             const float* __restrict__ stp,
                                             const float* __restrict__ bg,
                                             const float* __restrict__ bb,
                                             int hasbn,
                                             float* __restrict__ z) {
  __shared__ float t12[64 * 68];  // feat0+feat1 pre-sum, padded stride 68
  __shared__ float t3[8 * 68];
  __shared__ float nsb[128];      // ns[0..64), nb[64..128)
  const float* bt = bemb + (size_t)l * NBF * 8 * 64;
  const float4* bt4 = (const float4*)bt;
  for (int i = threadIdx.x; i < 64 * 16; i += 256) {
    int combo = i >> 4, ch4 = i & 15;
    float4 a = bt4[(combo & 7) * 16 + ch4];
    float4 b = bt4[128 + (combo >> 3) * 16 + ch4];
    float4 sum;
    sum.x = a.x + b.x; sum.y = a.y + b.y; sum.z = a.z + b.z; sum.w = a.w + b.w;
    *(float4*)(t12 + combo * 68 + ch4 * 4) = sum;
  }
  for (int i = threadIdx.x; i < 8 * 16; i += 256) {
    int row = i >> 4, ch4 = i & 15;
    *(float4*)(t3 + row * 68 + ch4 * 4) = bt4[256 + row * 16 + ch4];
  }
  if (hasbn && threadIdx.x < 64) {
    int c = threadIdx.x;
    const float inv = 1.0f / NN;
    float mu = stp[c] * inv;
    float var = stp[64 + c] * inv - mu * mu;
    float sc = rsqrtf(var + BN_EPS) * bg[c];
    nsb[c] = sc;
    nsb[64 + c] = bb[c] - mu * sc;
  }
  __syncthreads();
  const char* hbb = (const char*)hb;
  const float4* hf4 = (const float4*)hf;

  int lane = threadIdx.x & 63;
  int wid = threadIdx.x >> 6;
  int gr = lane >> 4;
  int c4 = lane & 15;
  int nbase = blockIdx.x * 16 + wid * 4;
  float se = 1.0f + eps[l];
  float4 ns4 = {1.f, 1.f, 1.f, 1.f}, nb4 = {0.f, 0.f, 0.f, 0.f};
  if (hasbn) {
    ns4 = ((const float4*)nsb)[c4];
    nb4 = ((const float4*)(nsb + 64))[c4];
  }

#pragma unroll
  for (int k = 0; k < 4; ++k) {
    int node = nbase + k;  // NN == gridDim*16, always valid
    int beg = row_ptr[node], end = row_ptr[node + 1];
    float4 acc = {0.f, 0.f, 0.f, 0.f};

    auto edge = [&](unsigned p, ushort4 hv) {
      unsigned cd = p >> 17;
      float4 e12 = *(const float4*)(t12 + (cd & 63) * 68 + c4 * 4);
      float4 e3 = *(const float4*)(t3 + (cd >> 6) * 68 + c4 * 4);
      acc.x += fmaxf(b2f(hv.x) + e12.x + e3.x, 0.f);
      acc.y += fmaxf(b2f(hv.y) + e12.y + e3.y, 0.f);
      acc.z += fmaxf(b2f(hv.z) + e12.z + e3.z, 0.f);
      acc.w += fmaxf(b2f(hv.w) + e12.w + e3.w, 0.f);
    };

    int i = beg + gr;
    for (; i + 12 < end; i += 16) {
      unsigned p0 = epack[i];
      unsigned p1 = epack[i + 4];
      unsigned p2 = epack[i + 8];
      unsigned p3 = epack[i + 12];
      ushort4 h0 = *(const ushort4*)(hbb + ((p0 & 0x1FFFFu) * 128u + c4 * 8u));
      ushort4 h1 = *(const ushort4*)(hbb + ((p1 & 0x1FFFFu) * 128u + c4 * 8u));
      ushort4 h2 = *(const ushort4*)(hbb + ((p2 & 0x1FFFFu) * 128u + c4 * 8u));
      ushort4 h3 = *(const ushort4*)(hbb + ((p3 & 0x1FFFFu) * 128u + c4 * 8u));
      edge(p0, h0); edge(p1, h1); edge(p2, h2); edge(p3, h3);
    }
    for (; i < end; i += 4) {
      unsigned p0 = epack[i];
      ushort4 h0 = *(const ushort4*)(hbb + ((p0 & 0x1FFFFu) * 128u + c4 * 8u));
      edge(p0, h0);
    }
#pragma unroll
    for (int off = 16; off <= 32; off <<= 1) {
      acc.x += __shfl_xor(acc.x, off);
      acc.y += __shfl_xor(acc.y, off);
      acc.z += __shfl_xor(acc.z, off);
      acc.w += __shfl_xor(acc.w, off);
    }
    if (gr == 0) {
      float4 self = hf4[(size_t)node * 16 + c4];
      if (hasbn) {
        self.x = fmaxf(fmaf(self.x, ns4.x, nb4.x), 0.f);
        self.y = fmaxf(fmaf(self.y, ns4.y, nb4.y), 0.f);
        self.z = fmaxf(fmaf(self.z, ns4.z, nb4.z), 0.f);
        self.w = fmaxf(fmaf(self.w, ns4.w, nb4.w), 0.f);
      }
      float4 out;
      out.x = fmaf(self.x, se, acc.x);
      out.y = fmaf(self.y, se, acc.y);
      out.z = fmaf(self.z, se, acc.z);
      out.w = fmaf(self.w, se, acc.w);
      ((float4*)z)[(size_t)node * 16 + c4] = out;
    }
  }
}

// ------------- MFMA gemm1: z[NN,64] @ w1 + b1 -> y(fp32) ; BN1 partials -----
__global__ __launch_bounds__(256) void k_mm1(const float* __restrict__ z,
                                             const bf16x8* __restrict__ pre1,
                                             const float* __restrict__ b1,
                                             int l, float* __restrict__ y,
                                             float* __restrict__ part1) {
  __shared__ float lz[2][16 * 68];  // 8.7 KB
  int tid = threadIdx.x;
  int lane = tid & 63;
  int wid = tid >> 6;
  int c = lane & 15;
  int g = lane >> 4;

  int t0 = blockIdx.x * 2;
  int ntl = (t0 + 1 < NTILE) ? 2 : 1;

  const float4* zt = (const float4*)(z + (size_t)t0 * 16 * 64);
  int nf4 = ntl * 256;
  for (int i = tid; i < nf4; i += 256) {
    float4 v = zt[i];
    int tile = i >> 8;
    int f4 = i & 255;
    int row = f4 >> 4, c4i = f4 & 15;
    *(float4*)(&lz[tile][row * 68 + c4i * 4]) = v;
  }

  bf16x8 Bf[2][2];
#pragma unroll
  for (int u = 0; u < 2; ++u)
#pragma unroll
    for (int kh = 0; kh < 2; ++kh)
      Bf[u][kh] = pre1[(((size_t)l * 8 + wid * 2 + u) * 2 + kh) * 64 + lane];
  float bias0 = b1[l * 128 + (wid * 2) * 16 + c];
  float bias1 = b1[l * 128 + (wid * 2 + 1) * 16 + c];

  __syncthreads();

  float ssum0 = 0.f, ssum1 = 0.f, sq0 = 0.f, sq1 = 0.f;

#pragma unroll
  for (int u = 0; u < 2; ++u) {
    if (u >= ntl) break;
    int rowbase = (t0 + u) * 16;
    const float* myz = lz[u];
    float4 q0 = *(const float4*)(myz + c * 68 + g * 8);
    float4 q1 = *(const float4*)(myz + c * 68 + g * 8 + 4);
    float4 q2 = *(const float4*)(myz + c * 68 + 32 + g * 8);
    float4 q3 = *(const float4*)(myz + c * 68 + 32 + g * 8 + 4);
    bf16x8 a0 = pack8(q0, q1);
    bf16x8 a1 = pack8(q2, q3);

    f32x4 acc0 = {bias0, bias0, bias0, bias0};
    acc0 = __builtin_amdgcn_mfma_f32_16x16x32_bf16(a0, Bf[0][0], acc0, 0, 0, 0);
    acc0 = __builtin_amdgcn_mfma_f32_16x16x32_bf16(a1, Bf[0][1], acc0, 0, 0, 0);
    f32x4 acc1 = {bias1, bias1, bias1, bias1};
    acc1 = __builtin_amdgcn_mfma_f32_16x16x32_bf16(a0, Bf[1][0], acc1, 0, 0, 0);
    acc1 = __builtin_amdgcn_mfma_f32_16x16x32_bf16(a1, Bf[1][1], acc1, 0, 0, 0);

    int tc0 = wid * 2, tc1 = wid * 2 + 1;
#pragma unroll
    for (int r = 0; r < 4; ++r) {
      float v0 = acc0[r], v1 = acc1[r];
      y[(size_t)(rowbase + g * 4 + r) * 128 + tc0 * 16 + c] = v0;
      y[(size_t)(rowbase + g * 4 + r) * 128 + tc1 * 16 + c] = v1;
      ssum0 += v0; sq0 = fmaf(v0, v0, sq0);
      ssum1 += v1; sq1 = fmaf(v1, v1, sq1);
    }
  }
  ssum0 += __shfl_xor(ssum0, 16); ssum0 += __shfl_xor(ssum0, 32);
  ssum1 += __shfl_xor(ssum1, 16); ssum1 += __shfl_xor(ssum1, 32);
  sq0 += __shfl_xor(sq0, 16); sq0 += __shfl_xor(sq0, 32);
  sq1 += __shfl_xor(sq1, 16); sq1 += __shfl_xor(sq1, 32);
  if (g == 0) {
    float* pp = part1 + (size_t)blockIdx.x * 256;
    pp[(wid * 2) * 16 + c] = ssum0;
    pp[(wid * 2 + 1) * 16 + c] = ssum1;
    pp[128 + (wid * 2) * 16 + c] = sq0;
    pp[128 + (wid * 2 + 1) * 16 + c] = sq1;
  }
}

// ---- MFMA gemm2: relu(bn1(y))[NN,128] @ w2 + b2 -> z2 ; BN2 partials --
__global__ __launch_bounds__(256) void k_mm2(const float* __restrict__ y,
                                             const bf16x8* __restrict__ pre2,
                                             const float* __restrict__ b2,
                                             const float* __restrict__ g1,
                                             const float* __restrict__ bb1,
                                             int l, float* __restrict__ z2,
                                             const float* __restrict__ st1,
                                             float* __restrict__ part2) {
  __shared__ float ly[2][16 * 132];  // 16.9 KB
  __shared__ float ns[128], nb[128];
  int tid = threadIdx.x;
  int lane = tid & 63;
  int wid = tid >> 6;
  int c = lane & 15;
  int g = lane >> 4;

  int t0 = blockIdx.x * 2;
  int ntl = (t0 + 1 < NTILE) ? 2 : 1;

  const float4* yt = (const float4*)(y + (size_t)t0 * 16 * 128);
  int nf4 = ntl * 512;
  for (int i = tid; i < nf4; i += 256) {
    float4 v = yt[i];
    int tile = i >> 9;
    int f4 = i & 511;
    int row = f4 >> 5, c4i = f4 & 31;
    *(float4*)(&ly[tile][row * 132 + c4i * 4]) = v;
  }

  if (tid < 128) {
    int ch = tid;
    const float inv = 1.0f / NN;
    float mu = st1[ch] * inv;
    float var = st1[128 + ch] * inv - mu * mu;
    float sc = rsqrtf(var + BN_EPS) * g1[l * 128 + ch];
    ns[ch] = sc;
    nb[ch] = bb1[l * 128 + ch] - mu * sc;
  }

  bf16x8 Bf[4];
#pragma unroll
  for (int kf = 0; kf < 4; ++kf)
    Bf[kf] = pre2[(((size_t)l * 4 + wid) * 4 + kf) * 64 + lane];
  float bias = b2[l * 64 + wid * 16 + c];

  __syncthreads();

  const float4* nsf = (const float4*)ns;
  const float4* nbf = (const float4*)nb;
  float ssum = 0.f, sq = 0.f;

#pragma unroll
  for (int u = 0; u < 2; ++u) {
    if (u >= ntl) break;
    int rowbase = (t0 + u) * 16;
    const float* myy = ly[u];
    bf16x8 A[4];
#pragma unroll
    for (int kf = 0; kf < 4; ++kf) {
      float4 q0 = *(const float4*)(myy + c * 132 + kf * 32 + g * 8);
      float4 q1 = *(const float4*)(myy + c * 132 + kf * 32 + g * 8 + 4);
      float4 s0 = nsf[kf * 8 + g * 2];
      float4 s1 = nsf[kf * 8 + g * 2 + 1];
      float4 o0 = nbf[kf * 8 + g * 2];
      float4 o1 = nbf[kf * 8 + g * 2 + 1];
      float4 v0, v1;
      v0.x = fmaxf(fmaf(q0.x, s0.x, o0.x), 0.f);
      v0.y = fmaxf(fmaf(q0.y, s0.y, o0.y), 0.f);
      v0.z = fmaxf(fmaf(q0.z, s0.z, o0.z), 0.f);
      v0.w = fmaxf(fmaf(q0.w, s0.w, o0.w), 0.f);
      v1.x = fmaxf(fmaf(q1.x, s1.x, o1.x), 0.f);
      v1.y = fmaxf(fmaf(q1.y, s1.y, o1.y), 0.f);
      v1.z = fmaxf(fmaf(q1.z, s1.z, o1.z), 0.f);
      v1.w = fmaxf(fmaf(q1.w, s1.w, o1.w), 0.f);
      A[kf] = pack8(v0, v1);
    }
    f32x4 acc = {bias, bias, bias, bias};
#pragma unroll
    for (int kf = 0; kf < 4; ++kf)
      acc = __builtin_amdgcn_mfma_f32_16x16x32_bf16(A[kf], Bf[kf], acc, 0, 0, 0);
#pragma unroll
    for (int r = 0; r < 4; ++r) {
      float v = acc[r];
      z2[(size_t)(rowbase + g * 4 + r) * 64 + wid * 16 + c] = v;
      ssum += v; sq = fmaf(v, v, sq);
    }
  }
  ssum += __shfl_xor(ssum, 16); ssum += __shfl_xor(ssum, 32);
  sq += __shfl_xor(sq, 16); sq += __shfl_xor(sq, 32);
  if (g == 0) {
    float* pp = part2 + (size_t)blockIdx.x * 128;
    pp[wid * 16 + c] = ssum;
    pp[64 + wid * 16 + c] = sq;
  }
}

// ------------- final BN2 apply (no relu) -> d_out -------------
__global__ __launch_bounds__(256) void k_bn2(const float* __restrict__ z2,
                                             const float* __restrict__ g,
                                             const float* __restrict__ b,
                                             const float* __restrict__ st,
                                             float* __restrict__ h) {
  __shared__ float ns[64], nb[64];
  if (threadIdx.x < 64) {
    int c = threadIdx.x;
    const float inv = 1.0f / NN;
    float mu = st[c] * inv;
    float var = st[64 + c] * inv - mu * mu;
    float sc = rsqrtf(var + BN_EPS) * g[c];
    ns[c] = sc;
    nb[c] = b[c] - mu * sc;
  }
  __syncthreads();
  const float4* zin = (const float4*)z2;
  float4* hout = (float4*)h;
  int total = NN * 16;
  for (int i = blockIdx.x * 256 + threadIdx.x; i < total; i += gridDim.x * 256) {
    float4 v = zin[i];
    int c = (i & 15) * 4;
    v.x = fmaf(v.x, ns[c], nb[c]);
    v.y = fmaf(v.y, ns[c + 1], nb[c + 1]);
    v.z = fmaf(v.z, ns[c + 2], nb[c + 2]);
    v.w = fmaf(v.w, ns[c + 3], nb[c + 3]);
    hout[i] = v;
  }
}

extern "C" void kernel_launch(void* const* d_in, const int* in_sizes, int n_in,
                              void* d_out, int out_size, void* d_ws, size_t ws_size,
                              hipStream_t stream) {
  const int* x = (const int*)d_in[0];
  const int* ei = (const int*)d_in[1];
  const int* ea = (const int*)d_in[2];
  const float* aemb = (const float*)d_in[3];
  const float* bemb = (const float*)d_in[4];
  const float* l1w = (const float*)d_in[5];
  const float* l1b = (const float*)d_in[6];
  const float* g1 = (const float*)d_in[7];
  const float* bb1 = (const float*)d_in[8];
  const float* l2w = (const float*)d_in[9];
  const float* l2b = (const float*)d_in[10];
  const float* eps = (const float*)d_in[11];
  const float* bng = (const float*)d_in[12];
  const float* bnb = (const float*)d_in[13];
  float* out = (float*)d_out;

  char* p = (char*)d_ws;
  float* zA = (float*)p;           p += (size_t)NN * 64 * 4;    // agg out
  float* y = (float*)p;            p += (size_t)NN * 128 * 4;   // y(fp32); hb+binned alias
  float* zB = (float*)p;           p += (size_t)NN * 64 * 4;    // gemm2 out (raw)
  unsigned* epack = (unsigned*)p;  p += (size_t)NE * 4;
  int* row_ptr = (int*)p;          p += (size_t)(NN + 1) * 4;
  int* bcnt = (int*)p;             p += 256 * 4;
  int* bbase = (int*)p;            p += 256 * 4;
  int* bfill = (int*)p;            p += 256 * 4;
  float* stats = (float*)p;        p += 4 * 384 * 4;
  bf16x8* pre1 = (bf16x8*)p;       p += 4096 * 16;
  bf16x8* pre2 = (bf16x8*)p;       p += 4096 * 16;
  float* part1 = (float*)p;        p += (size_t)MMB * 256 * 4;
  float* part2 = (float*)p;        p += (size_t)MMB * 128 * 4;

  uint2* binned = (uint2*)y;                // CSR phase only
  unsigned short* hb = (unsigned short*)y;  // bf16 h copy (pre-mm1 phase)
  float* h0 = zB;

  hipMemsetAsync(bcnt, 0, 3 * 256 * 4 + 4 * 384 * 4, stream);

  k_prep<<<32, 256, 0, stream>>>(l1w, l2w, pre1, pre2);
  k_hist2<<<256, 256, 0, stream>>>(ei, bcnt);
  k_scanb<<<1, 256, 0, stream>>>(bcnt, bbase, bfill);
  k_bin2<<<(NE + CHUNK - 1) / CHUNK, 1024, 0, stream>>>(ei, ea, bfill, binned);
  k_finAll<<<NBUK, 1024, 0, stream>>>(binned, bbase, bcnt, row_ptr, epack);

  k_atom<<<NN / 4, 256, 0, stream>>>(x, aemb, h0, hb);

  for (int l = 0; l < 4; ++l) {
    float* st1 = stats + l * 384;
    float* st2 = st1 + 256;
    const float* stp = (l > 0) ? (stats + (l - 1) * 384 + 256) : nullptr;
    const float* bgp = (l > 0) ? (bng + (l - 1) * 64) : nullptr;
    const float* bbp = (l > 0) ? (bnb + (l - 1) * 64) : nullptr;
    if (l > 0) {
      k_hprep<<<1024, 256, 0, stream>>>(zB, stp, bgp, bbp, hb);
    }
    k_agg<<<AGB, 256, 0, stream>>>(zB, hb, bemb, eps, l, row_ptr, epack,
                                   stp, bgp, bbp, (l > 0) ? 1 : 0, zA);
    k_mm1<<<MMB, 256, 0, stream>>>(zA, pre1, l1b, l, y, part1);
    k_red<<<32, 256, 0, stream>>>(part1, st1, 256);
    k_mm2<<<MMB, 256, 0, stream>>>(y, pre2, l2b, g1, bb1, l, zB, st1, part2);
    k_red<<<32, 256, 0, stream>>>(part2, st2, 128);
  }
  k_bn2<<<1024, 256, 0, stream>>>(zB, bng + 3 * 64, bnb + 3 * 64,
                                  stats + 3 * 384 + 256, out);
}

// Round 16
// 350.241 us; speedup vs baseline: 1.1578x; 1.0767x over previous
//
#include <hip/hip_runtime.h>
#include <hip/hip_bf16.h>

#define NN 50000
#define NE 800000
#define NAF 9
#define NBF 3
#define BN_EPS 1e-5f
#define NBUK 196          // ceil(NN/256) dst buckets
#define CHUNK 8192        // edges staged in LDS per k_bin block
#define NTILE 3125        // NN / 16 row tiles (exact)
#define MMB 1563          // mm grid: 2 row-tiles per block, one-shot
#define AGB 3125          // agg grid: 16 nodes per block (4 per wave)

typedef __attribute__((ext_vector_type(8))) short bf16x8;
typedef __attribute__((ext_vector_type(4))) float f32x4;

__device__ __forceinline__ short f2b(float f) {
  unsigned u = __float_as_uint(f);
  unsigned r = (u + 0x7FFFu + ((u >> 16) & 1u)) >> 16;
  return (short)r;
}

__device__ __forceinline__ float b2f(unsigned short v) {
  return __uint_as_float(((unsigned)v) << 16);
}

__device__ __forceinline__ bf16x8 pack8(float4 a, float4 b) {
  bf16x8 v;
  v[0] = f2b(a.x); v[1] = f2b(a.y); v[2] = f2b(a.z); v[3] = f2b(a.w);
  v[4] = f2b(b.x); v[5] = f2b(b.y); v[6] = f2b(b.z); v[7] = f2b(b.w);
  return v;
}

// ---------------- K0: atom encoder (fp32 h + bf16 copy) ----------------
__global__ __launch_bounds__(256) void k_atom(const int* __restrict__ x,
                                              const float* __restrict__ aemb,
                                              float* __restrict__ h,
                                              unsigned short* __restrict__ hb) {
  int node = (blockIdx.x * 256 + threadIdx.x) >> 6;
  int lane = threadIdx.x & 63;
  if (node >= NN) return;
  const int* xr = x + node * NAF;
  float acc = 0.f;
#pragma unroll
  for (int f = 0; f < NAF; ++f) acc += aemb[(f * 64 + xr[f]) * 64 + lane];
  h[(size_t)node * 64 + lane] = acc;
  hb[(size_t)node * 64 + lane] = (unsigned short)f2b(acc);
}

// -------- weight pre-pack: fragment-layout bf16 for all layers --------
__global__ __launch_bounds__(256) void k_prep(const float* __restrict__ w1,
                                              const float* __restrict__ w2,
                                              bf16x8* __restrict__ pre1,
                                              bf16x8* __restrict__ pre2) {
  int f = (blockIdx.x & 15) * 256 + threadIdx.x;  // 0..4095
  int lane = f & 63, c = lane & 15, g = lane >> 4;
  if (blockIdx.x < 16) {
    int kh = (f >> 6) & 1, t = (f >> 7) & 7, l = f >> 10;
    const float* w = w1 + (size_t)l * 64 * 128;
    bf16x8 v;
#pragma unroll
    for (int j = 0; j < 8; ++j) v[j] = f2b(w[(kh * 32 + g * 8 + j) * 128 + t * 16 + c]);
    pre1[f] = v;
  } else {
    int kf = (f >> 6) & 3, t = (f >> 8) & 3, l = f >> 10;
    const float* w = w2 + (size_t)l * 128 * 64;
    bf16x8 v;
#pragma unroll
    for (int j = 0; j < 8; ++j) v[j] = f2b(w[(kf * 32 + g * 8 + j) * 64 + t * 16 + c]);
    pre2[f] = v;
  }
}

// -------- partial-stats reduce --------
__global__ __launch_bounds__(256) void k_red(const float* __restrict__ partial,
                                             float* __restrict__ st, int width) {
  int col = threadIdx.x;
  if (col >= width) return;
  int per = (MMB + gridDim.x - 1) / gridDim.x;
  int r0 = blockIdx.x * per;
  int r1 = min(MMB, r0 + per);
  float s = 0.f;
  int r = r0;
  for (; r + 4 <= r1; r += 4) {
    s += partial[(size_t)r * width + col] + partial[(size_t)(r + 1) * width + col]
       + partial[(size_t)(r + 2) * width + col] + partial[(size_t)(r + 3) * width + col];
  }
  for (; r < r1; ++r) s += partial[(size_t)r * width + col];
  atomicAdd(&st[col], s);
}

// -------- h prep: in-place BN+ReLU on zB, emit bf16 copy --------
__global__ __launch_bounds__(256) void k_hprep(float* __restrict__ zB,
                                               const float* __restrict__ st,
                                               const float* __restrict__ g,
                                               const float* __restrict__ b,
                                               unsigned short* __restrict__ hb) {
  __shared__ float ns[64], nbv[64];
  if (threadIdx.x < 64) {
    int c = threadIdx.x;
    const float inv = 1.0f / NN;
    float mu = st[c] * inv;
    float var = st[64 + c] * inv - mu * mu;
    float sc = rsqrtf(var + BN_EPS) * g[c];
    ns[c] = sc;
    nbv[c] = b[c] - mu * sc;
  }
  __syncthreads();
  float4* z4 = (float4*)zB;
  ushort4* hb4 = (ushort4*)hb;
  int total = NN * 16;
  for (int i = blockIdx.x * 256 + threadIdx.x; i < total; i += gridDim.x * 256) {
    float4 v = z4[i];
    int c = (i & 15) * 4;
    v.x = fmaxf(fmaf(v.x, ns[c], nbv[c]), 0.f);
    v.y = fmaxf(fmaf(v.y, ns[c + 1], nbv[c + 1]), 0.f);
    v.z = fmaxf(fmaf(v.z, ns[c + 2], nbv[c + 2]), 0.f);
    v.w = fmaxf(fmaf(v.w, ns[c + 3], nbv[c + 3]), 0.f);
    z4[i] = v;
    ushort4 o;
    o.x = (unsigned short)f2b(v.x);
    o.y = (unsigned short)f2b(v.y);
    o.z = (unsigned short)f2b(v.z);
    o.w = (unsigned short)f2b(v.w);
    hb4[i] = o;
  }
}

// ---------------- CSR build: bucket hist -> scan -> bin -> finAll ----------------
__global__ __launch_bounds__(256) void k_hist2(const int* __restrict__ ei,
                                               int* __restrict__ bcnt) {
  __shared__ int lh[NBUK];
  for (int i = threadIdx.x; i < NBUK; i += 256) lh[i] = 0;
  __syncthreads();
  for (int e = blockIdx.x * 256 + threadIdx.x; e < NE; e += gridDim.x * 256)
    atomicAdd(&lh[ei[NE + e] >> 8], 1);
  __syncthreads();
  for (int i = threadIdx.x; i < NBUK; i += 256)
    if (lh[i]) atomicAdd(&bcnt[i], lh[i]);
}

__global__ __launch_bounds__(256) void k_scanb(const int* __restrict__ bcnt,
                                               int* __restrict__ bbase,
                                               int* __restrict__ bfill) {
  int tid = threadIdx.x;
  int c = (tid < NBUK) ? bcnt[tid] : 0;
  int lane = tid & 63, wid = tid >> 6;
  int inc = c;
#pragma unroll
  for (int off = 1; off < 64; off <<= 1) {
    int t = __shfl_up(inc, off);
    if (lane >= off) inc += t;
  }
  __shared__ int wt[4];
  if (lane == 63) wt[wid] = inc;
  __syncthreads();
  int woff = 0;
#pragma unroll
  for (int w = 0; w < 4; ++w) woff += (w < wid) ? wt[w] : 0;
  if (tid < NBUK) { int e = inc - c + woff; bbase[tid] = e; bfill[tid] = e; }
}

// bin: read ei/ea directly, build payload, LDS-stage, dense bucket writes
__global__ __launch_bounds__(1024) void k_bin2(const int* __restrict__ ei,
                                               const int* __restrict__ ea,
                                               int* __restrict__ bfill,
                                               uint2* __restrict__ binned) {
  __shared__ uint2 st[CHUNK];     // 64 KB
  __shared__ int lh[NBUK];
  __shared__ int gbase[NBUK];
  int tid = threadIdx.x;
  int base = blockIdx.x * CHUNK;
  int n = NE - base; if (n > CHUNK) n = CHUNK;
  for (int i = tid; i < NBUK; i += 1024) lh[i] = 0;
  __syncthreads();
  for (int i = tid; i < n; i += 1024) {
    int e = base + i;
    int src = ei[e];
    int dst = ei[NE + e];
    unsigned code = (unsigned)(ea[e * 3] | (ea[e * 3 + 1] << 3) | (ea[e * 3 + 2] << 6));
    st[i] = make_uint2((unsigned)src | (code << 17), (unsigned)dst);
    atomicAdd(&lh[dst >> 8], 1);
  }
  __syncthreads();
  for (int i = tid; i < NBUK; i += 1024) {
    int c = lh[i];
    gbase[i] = c ? atomicAdd(&bfill[i], c) : 0;
  }
  __syncthreads();
  for (int i = tid; i < NBUK; i += 1024) lh[i] = 0;
  __syncthreads();
  for (int i = tid; i < n; i += 1024) {
    uint2 p = st[i];
    int b = p.y >> 8;
    int r = atomicAdd(&lh[b], 1);
    binned[gbase[b] + r] = p;
  }
}

// finAll: per bucket: LDS count -> local scan -> row_ptr -> scatter.
__global__ __launch_bounds__(1024) void k_finAll(const uint2* __restrict__ binned,
                                                 const int* __restrict__ bbase,
                                                 const int* __restrict__ bcnt,
                                                 int* __restrict__ row_ptr,
                                                 unsigned* __restrict__ epack) {
  __shared__ int cnt[256];
  __shared__ int cur[256];
  __shared__ int wt[4];
  int b = blockIdx.x, tid = threadIdx.x;
  if (tid < 256) cnt[tid] = 0;
  __syncthreads();
  int s = bbase[b], n = bcnt[b];
  for (int i = tid; i < n; i += 1024) atomicAdd(&cnt[binned[s + i].y & 255], 1);
  __syncthreads();
  int lane = tid & 63, w = tid >> 6;
  int c = 0, inc = 0;
  if (tid < 256) {
    c = cnt[tid];
    inc = c;
#pragma unroll
    for (int off = 1; off < 64; off <<= 1) {
      int t = __shfl_up(inc, off);
      if (lane >= off) inc += t;
    }
    if (lane == 63) wt[w] = inc;
  }
  __syncthreads();
  if (tid < 256) {
    int woff = 0;
#pragma unroll
    for (int i = 0; i < 4; ++i) woff += (i < w) ? wt[i] : 0;
    int excl = s + inc - c + woff;
    int node = (b << 8) + tid;
    if (node < NN) row_ptr[node] = excl;
    cur[tid] = excl;
  }
  if (b == NBUK - 1 && tid == 0) row_ptr[NN] = NE;
  __syncthreads();
  for (int i = tid; i < n; i += 1024) {
    uint2 p = binned[s + i];
    int pos = atomicAdd(&cur[p.y & 255], 1);
    epack[pos] = p.x;
  }
}

// ------------- aggregation: bf16 gather + pre-summed bond tables -------------
// 16 nodes per block (4 per wave, sequential) to amortize the LDS table build.
__global__ __launch_bounds__(256) void k_agg(const float* __restrict__ hf,
                                             const unsigned short* __restrict__ hb,
                                             const float* __restrict__ bemb,
                                             const float* __restrict__ eps, int l,
                                             const int* __restrict__ row_ptr,
                                             const unsigned* __restrict__ epack,
                                             float* __restrict__ z) {
  __shared__ float t12[64 * 68];  // feat0+feat1 pre-sum, padded stride 68
  __shared__ float t3[8 * 68];
  const float* bt = bemb + (size_t)l * NBF * 8 * 64;
  const float4* bt4 = (const float4*)bt;
  for (int i = threadIdx.x; i < 64 * 16; i += 256) {
    int combo = i >> 4, ch4 = i & 15;
    float4 a = bt4[(combo & 7) * 16 + ch4];
    float4 b = bt4[128 + (combo >> 3) * 16 + ch4];
    float4 sum;
    sum.x = a.x + b.x; sum.y = a.y + b.y; sum.z = a.z + b.z; sum.w = a.w + b.w;
    *(float4*)(t12 + combo * 68 + ch4 * 4) = sum;
  }
  for (int i = threadIdx.x; i < 8 * 16; i += 256) {
    int row = i >> 4, ch4 = i & 15;
    *(float4*)(t3 + row * 68 + ch4 * 4) = bt4[256 + row * 16 + ch4];
  }
  __syncthreads();
  const char* hbb = (const char*)hb;
  const float4* hf4 = (const float4*)hf;

  int lane = threadIdx.x & 63;
  int wid = threadIdx.x >> 6;
  int gr = lane >> 4;
  int c4 = lane & 15;
  int nbase = blockIdx.x * 16 + wid * 4;
  float se = 1.0f + eps[l];

#pragma unroll
  for (int k = 0; k < 4; ++k) {
    int node = nbase + k;  // NN == gridDim*16, always valid
    int beg = row_ptr[node], end = row_ptr[node + 1];
    float4 acc = {0.f, 0.f, 0.f, 0.f};

    auto edge = [&](unsigned p, ushort4 hv) {
      unsigned cd = p >> 17;
      float4 e12 = *(const float4*)(t12 + (cd & 63) * 68 + c4 * 4);
      float4 e3 = *(const float4*)(t3 + (cd >> 6) * 68 + c4 * 4);
      acc.x += fmaxf(b2f(hv.x) + e12.x + e3.x, 0.f);
      acc.y += fmaxf(b2f(hv.y) + e12.y + e3.y, 0.f);
      acc.z += fmaxf(b2f(hv.z) + e12.z + e3.z, 0.f);
      acc.w += fmaxf(b2f(hv.w) + e12.w + e3.w, 0.f);
    };

    int i = beg + gr;
    for (; i + 12 < end; i += 16) {
      unsigned p0 = epack[i];
      unsigned p1 = epack[i + 4];
      unsigned p2 = epack[i + 8];
      unsigned p3 = epack[i + 12];
      ushort4 h0 = *(const ushort4*)(hbb + ((p0 & 0x1FFFFu) * 128u + c4 * 8u));
      ushort4 h1 = *(const ushort4*)(hbb + ((p1 & 0x1FFFFu) * 128u + c4 * 8u));
      ushort4 h2 = *(const ushort4*)(hbb + ((p2 & 0x1FFFFu) * 128u + c4 * 8u));
      ushort4 h3 = *(const ushort4*)(hbb + ((p3 & 0x1FFFFu) * 128u + c4 * 8u));
      edge(p0, h0); edge(p1, h1); edge(p2, h2); edge(p3, h3);
    }
    for (; i < end; i += 4) {
      unsigned p0 = epack[i];
      ushort4 h0 = *(const ushort4*)(hbb + ((p0 & 0x1FFFFu) * 128u + c4 * 8u));
      edge(p0, h0);
    }
#pragma unroll
    for (int off = 16; off <= 32; off <<= 1) {
      acc.x += __shfl_xor(acc.x, off);
      acc.y += __shfl_xor(acc.y, off);
      acc.z += __shfl_xor(acc.z, off);
      acc.w += __shfl_xor(acc.w, off);
    }
    if (gr == 0) {
      float4 self = hf4[(size_t)node * 16 + c4];
      float4 out;
      out.x = fmaf(self.x, se, acc.x);
      out.y = fmaf(self.y, se, acc.y);
      out.z = fmaf(self.z, se, acc.z);
      out.w = fmaf(self.w, se, acc.w);
      ((float4*)z)[(size_t)node * 16 + c4] = out;
    }
  }
}

// ------------- MFMA gemm1: z[NN,64] @ w1 + b1 -> y(fp32) ; BN1 partials -----
__global__ __launch_bounds__(256) void k_mm1(const float* __restrict__ z,
                                             const bf16x8* __restrict__ pre1,
                                             const float* __restrict__ b1,
                                             int l, float* __restrict__ y,
                                             float* __restrict__ part1) {
  __shared__ float lz[2][16 * 68];  // 8.7 KB
  int tid = threadIdx.x;
  int lane = tid & 63;
  int wid = tid >> 6;
  int c = lane & 15;
  int g = lane >> 4;

  int t0 = blockIdx.x * 2;
  int ntl = (t0 + 1 < NTILE) ? 2 : 1;

  const float4* zt = (const float4*)(z + (size_t)t0 * 16 * 64);
  int nf4 = ntl * 256;
  for (int i = tid; i < nf4; i += 256) {
    float4 v = zt[i];
    int tile = i >> 8;
    int f4 = i & 255;
    int row = f4 >> 4, c4i = f4 & 15;
    *(float4*)(&lz[tile][row * 68 + c4i * 4]) = v;
  }

  bf16x8 Bf[2][2];
#pragma unroll
  for (int u = 0; u < 2; ++u)
#pragma unroll
    for (int kh = 0; kh < 2; ++kh)
      Bf[u][kh] = pre1[(((size_t)l * 8 + wid * 2 + u) * 2 + kh) * 64 + lane];
  float bias0 = b1[l * 128 + (wid * 2) * 16 + c];
  float bias1 = b1[l * 128 + (wid * 2 + 1) * 16 + c];

  __syncthreads();

  float ssum0 = 0.f, ssum1 = 0.f, sq0 = 0.f, sq1 = 0.f;

#pragma unroll
  for (int u = 0; u < 2; ++u) {
    if (u >= ntl) break;
    int rowbase = (t0 + u) * 16;
    const float* myz = lz[u];
    float4 q0 = *(const float4*)(myz + c * 68 + g * 8);
    float4 q1 = *(const float4*)(myz + c * 68 + g * 8 + 4);
    float4 q2 = *(const float4*)(myz + c * 68 + 32 + g * 8);
    float4 q3 = *(const float4*)(myz + c * 68 + 32 + g * 8 + 4);
    bf16x8 a0 = pack8(q0, q1);
    bf16x8 a1 = pack8(q2, q3);

    f32x4 acc0 = {bias0, bias0, bias0, bias0};
    acc0 = __builtin_amdgcn_mfma_f32_16x16x32_bf16(a0, Bf[0][0], acc0, 0, 0, 0);
    acc0 = __builtin_amdgcn_mfma_f32_16x16x32_bf16(a1, Bf[0][1], acc0, 0, 0, 0);
    f32x4 acc1 = {bias1, bias1, bias1, bias1};
    acc1 = __builtin_amdgcn_mfma_f32_16x16x32_bf16(a0, Bf[1][0], acc1, 0, 0, 0);
    acc1 = __builtin_amdgcn_mfma_f32_16x16x32_bf16(a1, Bf[1][1], acc1, 0, 0, 0);

    int tc0 = wid * 2, tc1 = wid * 2 + 1;
#pragma unroll
    for (int r = 0; r < 4; ++r) {
      float v0 = acc0[r], v1 = acc1[r];
      y[(size_t)(rowbase + g * 4 + r) * 128 + tc0 * 16 + c] = v0;
      y[(size_t)(rowbase + g * 4 + r) * 128 + tc1 * 16 + c] = v1;
      ssum0 += v0; sq0 = fmaf(v0, v0, sq0);
      ssum1 += v1; sq1 = fmaf(v1, v1, sq1);
    }
  }
  ssum0 += __shfl_xor(ssum0, 16); ssum0 += __shfl_xor(ssum0, 32);
  ssum1 += __shfl_xor(ssum1, 16); ssum1 += __shfl_xor(ssum1, 32);
  sq0 += __shfl_xor(sq0, 16); sq0 += __shfl_xor(sq0, 32);
  sq1 += __shfl_xor(sq1, 16); sq1 += __shfl_xor(sq1, 32);
  if (g == 0) {
    float* pp = part1 + (size_t)blockIdx.x * 256;
    pp[(wid * 2) * 16 + c] = ssum0;
    pp[(wid * 2 + 1) * 16 + c] = ssum1;
    pp[128 + (wid * 2) * 16 + c] = sq0;
    pp[128 + (wid * 2 + 1) * 16 + c] = sq1;
  }
}

// ---- MFMA gemm2: relu(bn1(y))[NN,128] @ w2 + b2 -> z2 ; BN2 partials --
__global__ __launch_bounds__(256) void k_mm2(const float* __restrict__ y,
                                             const bf16x8* __restrict__ pre2,
                                             const float* __restrict__ b2,
                                             const float* __restrict__ g1,
                                             const float* __restrict__ bb1,
                                             int l, float* __restrict__ z2,
                                             const float* __restrict__ st1,
                                             float* __restrict__ part2) {
  __shared__ float ly[2][16 * 132];  // 16.9 KB
  __shared__ float ns[128], nb[128];
  int tid = threadIdx.x;
  int lane = tid & 63;
  int wid = tid >> 6;
  int c = lane & 15;
  int g = lane >> 4;

  int t0 = blockIdx.x * 2;
  int ntl = (t0 + 1 < NTILE) ? 2 : 1;

  const float4* yt = (const float4*)(y + (size_t)t0 * 16 * 128);
  int nf4 = ntl * 512;
  for (int i = tid; i < nf4; i += 256) {
    float4 v = yt[i];
    int tile = i >> 9;
    int f4 = i & 511;
    int row = f4 >> 5, c4i = f4 & 31;
    *(float4*)(&ly[tile][row * 132 + c4i * 4]) = v;
  }

  if (tid < 128) {
    int ch = tid;
    const float inv = 1.0f / NN;
    float mu = st1[ch] * inv;
    float var = st1[128 + ch] * inv - mu * mu;
    float sc = rsqrtf(var + BN_EPS) * g1[l * 128 + ch];
    ns[ch] = sc;
    nb[ch] = bb1[l * 128 + ch] - mu * sc;
  }

  bf16x8 Bf[4];
#pragma unroll
  for (int kf = 0; kf < 4; ++kf)
    Bf[kf] = pre2[(((size_t)l * 4 + wid) * 4 + kf) * 64 + lane];
  float bias = b2[l * 64 + wid * 16 + c];

  __syncthreads();

  const float4* nsf = (const float4*)ns;
  const float4* nbf = (const float4*)nb;
  float ssum = 0.f, sq = 0.f;

#pragma unroll
  for (int u = 0; u < 2; ++u) {
    if (u >= ntl) break;
    int rowbase = (t0 + u) * 16;
    const float* myy = ly[u];
    bf16x8 A[4];
#pragma unroll
    for (int kf = 0; kf < 4; ++kf) {
      float4 q0 = *(const float4*)(myy + c * 132 + kf * 32 + g * 8);
      float4 q1 = *(const float4*)(myy + c * 132 + kf * 32 + g * 8 + 4);
      float4 s0 = nsf[kf * 8 + g * 2];
      float4 s1 = nsf[kf * 8 + g * 2 + 1];
      float4 o0 = nbf[kf * 8 + g * 2];
      float4 o1 = nbf[kf * 8 + g * 2 + 1];
      float4 v0, v1;
      v0.x = fmaxf(fmaf(q0.x, s0.x, o0.x), 0.f);
      v0.y = fmaxf(fmaf(q0.y, s0.y, o0.y), 0.f);
      v0.z = fmaxf(fmaf(q0.z, s0.z, o0.z), 0.f);
      v0.w = fmaxf(fmaf(q0.w, s0.w, o0.w), 0.f);
      v1.x = fmaxf(fmaf(q1.x, s1.x, o1.x), 0.f);
      v1.y = fmaxf(fmaf(q1.y, s1.y, o1.y), 0.f);
      v1.z = fmaxf(fmaf(q1.z, s1.z, o1.z), 0.f);
      v1.w = fmaxf(fmaf(q1.w, s1.w, o1.w), 0.f);
      A[kf] = pack8(v0, v1);
    }
    f32x4 acc = {bias, bias, bias, bias};
#pragma unroll
    for (int kf = 0; kf < 4; ++kf)
      acc = __builtin_amdgcn_mfma_f32_16x16x32_bf16(A[kf], Bf[kf], acc, 0, 0, 0);
#pragma unroll
    for (int r = 0; r < 4; ++r) {
      float v = acc[r];
      z2[(size_t)(rowbase + g * 4 + r) * 64 + wid * 16 + c] = v;
      ssum += v; sq = fmaf(v, v, sq);
    }
  }
  ssum += __shfl_xor(ssum, 16); ssum += __shfl_xor(ssum, 32);
  sq += __shfl_xor(sq, 16); sq += __shfl_xor(sq, 32);
  if (g == 0) {
    float* pp = part2 + (size_t)blockIdx.x * 128;
    pp[wid * 16 + c] = ssum;
    pp[64 + wid * 16 + c] = sq;
  }
}

// ------------- final BN2 apply (no relu) -> d_out -------------
__global__ __launch_bounds__(256) void k_bn2(const float* __restrict__ z2,
                                             const float* __restrict__ g,
                                             const float* __restrict__ b,
                                             const float* __restrict__ st,
                                             float* __restrict__ h) {
  __shared__ float ns[64], nb[64];
  if (threadIdx.x < 64) {
    int c = threadIdx.x;
    const float inv = 1.0f / NN;
    float mu = st[c] * inv;
    float var = st[64 + c] * inv - mu * mu;
    float sc = rsqrtf(var + BN_EPS) * g[c];
    ns[c] = sc;
    nb[c] = b[c] - mu * sc;
  }
  __syncthreads();
  const float4* zin = (const float4*)z2;
  float4* hout = (float4*)h;
  int total = NN * 16;
  for (int i = blockIdx.x * 256 + threadIdx.x; i < total; i += gridDim.x * 256) {
    float4 v = zin[i];
    int c = (i & 15) * 4;
    v.x = fmaf(v.x, ns[c], nb[c]);
    v.y = fmaf(v.y, ns[c + 1], nb[c + 1]);
    v.z = fmaf(v.z, ns[c + 2], nb[c + 2]);
    v.w = fmaf(v.w, ns[c + 3], nb[c + 3]);
    hout[i] = v;
  }
}

extern "C" void kernel_launch(void* const* d_in, const int* in_sizes, int n_in,
                              void* d_out, int out_size, void* d_ws, size_t ws_size,
                              hipStream_t stream) {
  const int* x = (const int*)d_in[0];
  const int* ei = (const int*)d_in[1];
  const int* ea = (const int*)d_in[2];
  const float* aemb = (const float*)d_in[3];
  const float* bemb = (const float*)d_in[4];
  const float* l1w = (const float*)d_in[5];
  const float* l1b = (const float*)d_in[6];
  const float* g1 = (const float*)d_in[7];
  const float* bb1 = (const float*)d_in[8];
  const float* l2w = (const float*)d_in[9];
  const float* l2b = (const float*)d_in[10];
  const float* eps = (const float*)d_in[11];
  const float* bng = (const float*)d_in[12];
  const float* bnb = (const float*)d_in[13];
  float* out = (float*)d_out;

  char* p = (char*)d_ws;
  float* zA = (float*)p;           p += (size_t)NN * 64 * 4;    // agg out
  float* y = (float*)p;            p += (size_t)NN * 128 * 4;   // y(fp32); hb+binned alias
  float* zB = (float*)p;           p += (size_t)NN * 64 * 4;    // gemm2 out / h (in-place BN)
  unsigned* epack = (unsigned*)p;  p += (size_t)NE * 4;
  int* row_ptr = (int*)p;          p += (size_t)(NN + 1) * 4;
  int* bcnt = (int*)p;             p += 256 * 4;
  int* bbase = (int*)p;            p += 256 * 4;
  int* bfill = (int*)p;            p += 256 * 4;
  float* stats = (float*)p;        p += 4 * 384 * 4;
  bf16x8* pre1 = (bf16x8*)p;       p += 4096 * 16;
  bf16x8* pre2 = (bf16x8*)p;       p += 4096 * 16;
  float* part1 = (float*)p;        p += (size_t)MMB * 256 * 4;
  float* part2 = (float*)p;        p += (size_t)MMB * 128 * 4;

  uint2* binned = (uint2*)y;                // CSR phase only
  unsigned short* hb = (unsigned short*)y;  // bf16 h copy (pre-mm1 phase)
  float* h0 = zB;

  hipMemsetAsync(bcnt, 0, 3 * 256 * 4 + 4 * 384 * 4, stream);

  k_prep<<<32, 256, 0, stream>>>(l1w, l2w, pre1, pre2);
  k_hist2<<<256, 256, 0, stream>>>(ei, bcnt);
  k_scanb<<<1, 256, 0, stream>>>(bcnt, bbase, bfill);
  k_bin2<<<(NE + CHUNK - 1) / CHUNK, 1024, 0, stream>>>(ei, ea, bfill, binned);
  k_finAll<<<NBUK, 1024, 0, stream>>>(binned, bbase, bcnt, row_ptr, epack);

  k_atom<<<NN / 4, 256, 0, stream>>>(x, aemb, h0, hb);

  for (int l = 0; l < 4; ++l) {
    float* st1 = stats + l * 384;
    float* st2 = st1 + 256;
    if (l > 0) {
      const float* stp = stats + (l - 1) * 384 + 256;
      k_hprep<<<1024, 256, 0, stream>>>(zB, stp, bng + (l - 1) * 64,
                                        bnb + (l - 1) * 64, hb);
    }
    k_agg<<<AGB, 256, 0, stream>>>(zB, hb, bemb, eps, l, row_ptr, epack, zA);
    k_mm1<<<MMB, 256, 0, stream>>>(zA, pre1, l1b, l, y, part1);
    k_red<<<32, 256, 0, stream>>>(part1, st1, 256);
    k_mm2<<<MMB, 256, 0, stream>>>(y, pre2, l2b, g1, bb1, l, zB, st1, part2);
    k_red<<<32, 256, 0, stream>>>(part2, st2, 128);
  }
  k_bn2<<<1024, 256, 0, stream>>>(zB, bng + 3 * 64, bnb + 3 * 64,
                                  stats + 3 * 384 + 256, out);
}